// Round 5
// baseline (508.751 us; speedup 1.0000x reference)
//
#include <hip/hip_runtime.h>
#include <stdint.h>

// Problem constants (fixed by the reference)
constexpr int BB = 8;
constexpr int LL = 4096;
constexpr int DD = 128;
constexpr int KC = 1024;
constexpr int NN = BB * LL;          // 32768
constexpr int ZTOT = BB * DD * LL;   // 4194304

// Threefry variant: 1 = partitionable (JAX >= 0.4.36 default), 0 = original
#define THREEFRY_PARTITIONABLE 1

__device__ __forceinline__ uint32_t rotl32(uint32_t x, int r) {
  return (x << r) | (x >> (32 - r));
}

__device__ __forceinline__ void threefry2x32(uint32_t k0, uint32_t k1,
                                             uint32_t x0, uint32_t x1,
                                             uint32_t* o0, uint32_t* o1) {
  uint32_t ks0 = k0, ks1 = k1, ks2 = 0x1BD11BDAu ^ k0 ^ k1;
  x0 += ks0; x1 += ks1;
  // group 1: rot 13,15,26,6
  x0 += x1; x1 = rotl32(x1, 13); x1 ^= x0;
  x0 += x1; x1 = rotl32(x1, 15); x1 ^= x0;
  x0 += x1; x1 = rotl32(x1, 26); x1 ^= x0;
  x0 += x1; x1 = rotl32(x1, 6);  x1 ^= x0;
  x0 += ks1; x1 += ks2 + 1u;
  // group 2: rot 17,29,16,24
  x0 += x1; x1 = rotl32(x1, 17); x1 ^= x0;
  x0 += x1; x1 = rotl32(x1, 29); x1 ^= x0;
  x0 += x1; x1 = rotl32(x1, 16); x1 ^= x0;
  x0 += x1; x1 = rotl32(x1, 24); x1 ^= x0;
  x0 += ks2; x1 += ks0 + 2u;
  // group 3: rot 13,15,26,6
  x0 += x1; x1 = rotl32(x1, 13); x1 ^= x0;
  x0 += x1; x1 = rotl32(x1, 15); x1 ^= x0;
  x0 += x1; x1 = rotl32(x1, 26); x1 ^= x0;
  x0 += x1; x1 = rotl32(x1, 6);  x1 ^= x0;
  x0 += ks0; x1 += ks1 + 3u;
  // group 4: rot 17,29,16,24
  x0 += x1; x1 = rotl32(x1, 17); x1 ^= x0;
  x0 += x1; x1 = rotl32(x1, 29); x1 ^= x0;
  x0 += x1; x1 = rotl32(x1, 16); x1 ^= x0;
  x0 += x1; x1 = rotl32(x1, 24); x1 ^= x0;
  x0 += ks1; x1 += ks2 + 4u;
  // group 5: rot 13,15,26,6
  x0 += x1; x1 = rotl32(x1, 13); x1 ^= x0;
  x0 += x1; x1 = rotl32(x1, 15); x1 ^= x0;
  x0 += x1; x1 = rotl32(x1, 26); x1 ^= x0;
  x0 += x1; x1 = rotl32(x1, 6);  x1 ^= x0;
  x0 += ks2; x1 += ks0 + 5u;
  *o0 = x0; *o1 = x1;
}

// Kernel 0: e_sq per code, zero accumulators
__global__ __launch_bounds__(128) void k_prep(const float* __restrict__ E,
                                              float* __restrict__ esq,
                                              float* __restrict__ wsum,
                                              float* __restrict__ counts,
                                              double* __restrict__ lacc) {
  const int k = blockIdx.x;       // 1024 blocks
  const int d = threadIdx.x;      // 128 threads
  float v = E[k * DD + d];
  __shared__ float r[128];
  r[d] = v * v;
  __syncthreads();
  for (int s = 64; s > 0; s >>= 1) {
    if (d < s) r[d] += r[d + s];
    __syncthreads();
  }
  if (d == 0) {
    esq[k] = r[0];
    counts[k] = 0.0f;
    if (k == 0) lacc[0] = 0.0;
  }
  wsum[k * DD + d] = 0.0f;
}

// Kernel 1: per-row argmin over K codes + counts + weighted sums
// block = 256 threads = 4 waves; 64 rows per block; wave w scans codes [w*256, w*256+256)
__global__ __launch_bounds__(256) void k_argmin(const float* __restrict__ Z,
                                                const float* __restrict__ E,
                                                const float* __restrict__ esq,
                                                int* __restrict__ idx_out,
                                                float* __restrict__ counts,
                                                float* __restrict__ wsum) {
  const int lane = threadIdx.x & 63;
  const int w = __builtin_amdgcn_readfirstlane((int)(threadIdx.x >> 6));
  const int row = blockIdx.x * 64 + lane;
  const int b = row >> 12;            // / 4096
  const int l = row & (LL - 1);
  const float* zp = Z + (size_t)b * DD * LL + l;

  float z[DD];
#pragma unroll
  for (int d = 0; d < DD; ++d) z[d] = zp[(size_t)d * LL];

  float zsq = 0.0f;
#pragma unroll
  for (int d = 0; d < DD; ++d) zsq = fmaf(z[d], z[d], zsq);

  float best = 3.4e38f;
  int bidx = 0;
  const int k0 = w * 256;
  for (int k = k0; k < k0 + 256; ++k) {
    const float* __restrict__ ek = E + (size_t)k * DD;   // wave-uniform -> s_load
    float a0 = 0.f, a1 = 0.f, a2 = 0.f, a3 = 0.f;
#pragma unroll
    for (int d = 0; d < DD; d += 4) {
      a0 = fmaf(ek[d + 0], z[d + 0], a0);
      a1 = fmaf(ek[d + 1], z[d + 1], a1);
      a2 = fmaf(ek[d + 2], z[d + 2], a2);
      a3 = fmaf(ek[d + 3], z[d + 3], a3);
    }
    float dot = (a0 + a1) + (a2 + a3);
    float key = (zsq + esq[k]) - 2.0f * dot;   // matches reference expr tree
    if (key < best) { best = key; bidx = k; }  // strict < => first-index tie-break
  }

  __shared__ float sb[4][64];
  __shared__ int si[4][64];
  sb[w][lane] = best;
  si[w][lane] = bidx;
  __syncthreads();

  // combine 4 wave candidates (ascending k ranges; strict < keeps lowest k on ties)
  float fb = sb[0][lane];
  int fi = si[0][lane];
#pragma unroll
  for (int j = 1; j < 4; ++j) {
    float v = sb[j][lane];
    int i2 = si[j][lane];
    if (v < fb) { fb = v; fi = i2; }
  }

  if (w == 0) {
    idx_out[row] = fi;
    atomicAdd(&counts[fi], 1.0f);   // integer-valued fp32: exact, deterministic
  }
  // each wave scatters its 32-d slice of the row into wsum
  float* wrow = wsum + (size_t)fi * DD;
#pragma unroll
  for (int d = 0; d < DD; ++d) {
    if ((d >> 5) == w) atomicAdd(&wrow[d], z[d]);
  }
}

// Kernel 2: cluster-size EMA, dead detection, threefry restart indices, smoothing
__global__ __launch_bounds__(1024) void k_cluster(const float* __restrict__ counts,
                                                  const float* __restrict__ cs_in,
                                                  float* __restrict__ smooth,
                                                  int* __restrict__ ridx,
                                                  int* __restrict__ deadf) {
  const int k = threadIdx.x;   // 1024 threads, 1 block
  float c = counts[k];
  float t1 = 0.99f * cs_in[k];
  float t2 = 0.01f * c;        // f32(1.0 - 0.99) == f32(0.01)
  float nc = t1 + t2;
  bool dead = nc < 0.5f;

  uint32_t bits;
#if THREEFRY_PARTITIONABLE
  {
    uint32_t o0, o1;
    threefry2x32(0u, 42u, 0u, (uint32_t)k, &o0, &o1);  // counter = (hi=0, lo=k)
    bits = o0 ^ o1;
  }
#else
  {
    uint32_t o0, o1;
    if (k < 512) { threefry2x32(0u, 42u, (uint32_t)k, (uint32_t)(k + 512), &o0, &o1); bits = o0; }
    else         { threefry2x32(0u, 42u, (uint32_t)(k - 512), (uint32_t)k, &o0, &o1); bits = o1; }
  }
#endif
  int r = (int)(bits & 0x7FFFu);   // span=32768 (pow2): randint == bits mod 2^15

  float rep = dead ? 0.5f : nc;

  __shared__ float red[1024];
  red[k] = rep;
  __syncthreads();
  for (int s = 512; s > 0; s >>= 1) {
    if (k < s) red[k] += red[k + s];
    __syncthreads();
  }
  float n = red[0];

  float sm = ((rep + 1e-5f) / (n + 0.01024f)) * n;   // (nc+EPS)/(n+K*EPS)*n
  smooth[k] = sm;
  ridx[k] = r;
  deadf[k] = dead ? 1 : 0;
}

// Kernel 3: new embedding = (EMA avg or restart vec) / smoothed
__global__ __launch_bounds__(256) void k_emb(const float* __restrict__ wsum,
                                             const float* __restrict__ avg_in,
                                             const float* __restrict__ Z,
                                             const float* __restrict__ smooth,
                                             const int* __restrict__ ridx,
                                             const int* __restrict__ deadf,
                                             float* __restrict__ nemb) {
  int kd = blockIdx.x * 256 + threadIdx.x;   // < 131072
  int k = kd >> 7;
  int d = kd & (DD - 1);
  float t1 = 0.99f * avg_in[kd];
  float t2 = 0.01f * wsum[kd];
  float na = t1 + t2;
  if (deadf[k]) {
    int r = ridx[k];
    float zv = Z[((size_t)(r >> 12) * DD + d) * LL + (r & (LL - 1))];
    na = zv * 0.5f;   // rvec * RESTART_THRESHOLD
  }
  nemb[kd] = na / smooth[k];
}

// Kernel 4: gather z_q, write z_q_st + indices_map, accumulate squared-error
__global__ __launch_bounds__(256) void k_out(const float* __restrict__ Z,
                                             const float* __restrict__ nemb,
                                             const int* __restrict__ idxs,
                                             float* __restrict__ out,
                                             double* __restrict__ lacc) {
  int t = blockIdx.x * 256 + threadIdx.x;   // 1048576 threads, 4 l-elems each
  int l4 = t & (LL / 4 - 1);                // 1024
  int d = (t >> 10) & (DD - 1);
  int b = t >> 17;
  size_t zoff = ((size_t)(b * DD + d)) * LL + (size_t)l4 * 4;
  const float4 ze = *(const float4*)(Z + zoff);
  int n0 = b * LL + l4 * 4;
  int i0 = idxs[n0 + 0], i1 = idxs[n0 + 1], i2 = idxs[n0 + 2], i3 = idxs[n0 + 3];
  float q0 = nemb[(size_t)i0 * DD + d];
  float q1 = nemb[(size_t)i1 * DD + d];
  float q2 = nemb[(size_t)i2 * DD + d];
  float q3 = nemb[(size_t)i3 * DD + d];
  float4 o;
  o.x = ze.x + (q0 - ze.x);   // z_q_st = z_e + (z_q - z_e), reference expr tree
  o.y = ze.y + (q1 - ze.y);
  o.z = ze.z + (q2 - ze.z);
  o.w = ze.w + (q3 - ze.w);
  *(float4*)(out + zoff) = o;
  if (d == 0) {
    float* oi = out + (size_t)ZTOT;
    oi[n0 + 0] = (float)i0;
    oi[n0 + 1] = (float)i1;
    oi[n0 + 2] = (float)i2;
    oi[n0 + 3] = (float)i3;
  }
  float d0 = ze.x - q0, d1 = ze.y - q1, d2 = ze.z - q2, d3 = ze.w - q3;
  float s = d0 * d0 + d1 * d1 + d2 * d2 + d3 * d3;
  for (int off = 32; off > 0; off >>= 1) s += __shfl_down(s, off, 64);
  __shared__ float wsums[4];
  if ((threadIdx.x & 63) == 0) wsums[threadIdx.x >> 6] = s;
  __syncthreads();
  if (threadIdx.x == 0) {
    float tot = (wsums[0] + wsums[1]) + (wsums[2] + wsums[3]);
    atomicAdd(lacc, (double)tot);
  }
}

// Kernel 5: final loss scalars
__global__ void k_fin(const double* __restrict__ lacc, float* __restrict__ out) {
  double S = lacc[0];
  float cb = (float)(S / (double)ZTOT);   // codebook_loss == commitment_loss numerically
  float bc = 0.25f * cb;
  float vq = cb + bc;
  float* o = out + (size_t)ZTOT + NN;
  o[0] = vq;
  o[1] = cb;
  o[2] = bc;
}

extern "C" void kernel_launch(void* const* d_in, const int* in_sizes, int n_in,
                              void* d_out, int out_size, void* d_ws, size_t ws_size,
                              hipStream_t stream) {
  const float* Z  = (const float*)d_in[0];   // z_e        (8,128,4096)
  const float* E  = (const float*)d_in[1];   // embedding  (1024,128)
  const float* CS = (const float*)d_in[2];   // cluster_size (1024,)
  const float* EA = (const float*)d_in[3];   // embedding_avg (1024,128)
  float* out = (float*)d_out;
  float* ws = (float*)d_ws;

  float* counts = ws;                        // 1024
  float* esq    = ws + 1024;                 // 1024
  float* smooth = ws + 2048;                 // 1024
  int*   ridx   = (int*)(ws + 3072);         // 1024
  int*   deadf  = (int*)(ws + 4096);         // 1024
  float* wsum   = ws + 8192;                 // 131072
  float* nemb   = ws + 8192 + 131072;        // 131072
  int*   idxs   = (int*)(ws + 270336);       // 32768
  double* lacc  = (double*)(ws + 303104);    // byte offset 1212416, 8B aligned

  k_prep<<<KC, DD, 0, stream>>>(E, esq, wsum, counts, lacc);
  k_argmin<<<NN / 64, 256, 0, stream>>>(Z, E, esq, idxs, counts, wsum);
  k_cluster<<<1, KC, 0, stream>>>(counts, CS, smooth, ridx, deadf);
  k_emb<<<(KC * DD) / 256, 256, 0, stream>>>(wsum, EA, Z, smooth, ridx, deadf, nemb);
  k_out<<<(ZTOT / 4) / 256, 256, 0, stream>>>(Z, nemb, idxs, out, lacc);
  k_fin<<<1, 1, 0, stream>>>(lacc, out);
}

// Round 6
// 401.597 us; speedup vs baseline: 1.2668x; 1.2668x over previous
//
#include <hip/hip_runtime.h>
#include <stdint.h>

// Problem constants (fixed by the reference)
constexpr int BB = 8;
constexpr int LL = 4096;
constexpr int DD = 128;
constexpr int KC = 1024;
constexpr int NN = BB * LL;          // 32768
constexpr int ZTOT = BB * DD * LL;   // 4194304

// Threefry variant: 1 = partitionable (JAX >= 0.4.36 default), 0 = original
#define THREEFRY_PARTITIONABLE 1

__device__ __forceinline__ uint32_t rotl32(uint32_t x, int r) {
  return (x << r) | (x >> (32 - r));
}

__device__ __forceinline__ void threefry2x32(uint32_t k0, uint32_t k1,
                                             uint32_t x0, uint32_t x1,
                                             uint32_t* o0, uint32_t* o1) {
  uint32_t ks0 = k0, ks1 = k1, ks2 = 0x1BD11BDAu ^ k0 ^ k1;
  x0 += ks0; x1 += ks1;
  // group 1: rot 13,15,26,6
  x0 += x1; x1 = rotl32(x1, 13); x1 ^= x0;
  x0 += x1; x1 = rotl32(x1, 15); x1 ^= x0;
  x0 += x1; x1 = rotl32(x1, 26); x1 ^= x0;
  x0 += x1; x1 = rotl32(x1, 6);  x1 ^= x0;
  x0 += ks1; x1 += ks2 + 1u;
  // group 2: rot 17,29,16,24
  x0 += x1; x1 = rotl32(x1, 17); x1 ^= x0;
  x0 += x1; x1 = rotl32(x1, 29); x1 ^= x0;
  x0 += x1; x1 = rotl32(x1, 16); x1 ^= x0;
  x0 += x1; x1 = rotl32(x1, 24); x1 ^= x0;
  x0 += ks2; x1 += ks0 + 2u;
  // group 3: rot 13,15,26,6
  x0 += x1; x1 = rotl32(x1, 13); x1 ^= x0;
  x0 += x1; x1 = rotl32(x1, 15); x1 ^= x0;
  x0 += x1; x1 = rotl32(x1, 26); x1 ^= x0;
  x0 += x1; x1 = rotl32(x1, 6);  x1 ^= x0;
  x0 += ks0; x1 += ks1 + 3u;
  // group 4: rot 17,29,16,24
  x0 += x1; x1 = rotl32(x1, 17); x1 ^= x0;
  x0 += x1; x1 = rotl32(x1, 29); x1 ^= x0;
  x0 += x1; x1 = rotl32(x1, 16); x1 ^= x0;
  x0 += x1; x1 = rotl32(x1, 24); x1 ^= x0;
  x0 += ks1; x1 += ks2 + 4u;
  // group 5: rot 13,15,26,6
  x0 += x1; x1 = rotl32(x1, 13); x1 ^= x0;
  x0 += x1; x1 = rotl32(x1, 15); x1 ^= x0;
  x0 += x1; x1 = rotl32(x1, 26); x1 ^= x0;
  x0 += x1; x1 = rotl32(x1, 6);  x1 ^= x0;
  x0 += ks2; x1 += ks0 + 5u;
  *o0 = x0; *o1 = x1;
}

// Kernel 0: e_sq per code, E transpose (ET[d][k]), zero accumulators
__global__ __launch_bounds__(128) void k_prep(const float* __restrict__ E,
                                              float* __restrict__ esq,
                                              float* __restrict__ wsum,
                                              float* __restrict__ counts,
                                              double* __restrict__ lacc,
                                              float* __restrict__ ET) {
  const int k = blockIdx.x;       // 1024 blocks (codes)
  const int d = threadIdx.x;      // 128 threads (dims)
  float v = E[k * DD + d];
  ET[(size_t)d * KC + k] = v;     // transposed codebook for k_dist staging
  __shared__ float r[128];
  r[d] = v * v;
  __syncthreads();
  for (int s = 64; s > 0; s >>= 1) {
    if (d < s) r[d] += r[d + s];
    __syncthreads();
  }
  if (d == 0) {
    esq[k] = r[0];
    counts[k] = 0.0f;
    if (k == 0) lacc[0] = 0.0;
  }
  wsum[k * DD + d] = 0.0f;
}

// Kernel 1: LDS-tiled distance GEMM + per-row argmin + counts + weighted sums.
// Block: 256 threads, 64 rows x (16 chunks of 64 codes), K=128.
// Per-thread 4 rows x 4 codes register tile; operands in LDS as [d][row]/[d][code].
__global__ __launch_bounds__(256) void k_dist(const float* __restrict__ Z,
                                              const float* __restrict__ ET,
                                              const float* __restrict__ esq,
                                              int* __restrict__ idx_out,
                                              float* __restrict__ counts,
                                              float* __restrict__ wsum) {
  __shared__ float Zt[128][64];   // 32 KB
  __shared__ float Et[128][64];   // 32 KB
  __shared__ float cval[16][64];  // 4 KB
  __shared__ int   cidx[16][64];  // 4 KB
  __shared__ int   fidx[64];

  const int tid = threadIdx.x;
  const int tx = tid & 15;        // row group: rows tx*4 .. tx*4+3
  const int ty = tid >> 4;        // code group: codes ty*4 .. ty*4+3 (within chunk)
  const int r0 = blockIdx.x * 64; // 64 rows per block, all in one batch b
  const int b  = r0 >> 12;
  const int l0 = r0 & (LL - 1);

  // stage Z tile -> Zt[d][row]; global reads 64-float contiguous per d (coalesced)
  const float* zsrc = Z + (size_t)b * DD * LL + l0;
#pragma unroll
  for (int p = 0; p < 8; ++p) {
    int idx = p * 256 + tid;
    int d = idx >> 4;
    int cc = idx & 15;
    float4 v = *(const float4*)(zsrc + (size_t)d * LL + cc * 4);
    *(float4*)(&Zt[d][cc * 4]) = v;
  }
  __syncthreads();

  // zsq for this thread's 4 rows
  float zsq[4] = {0.f, 0.f, 0.f, 0.f};
#pragma unroll 8
  for (int k = 0; k < 128; ++k) {
    float4 zv = *(const float4*)(&Zt[k][tx * 4]);
    zsq[0] = fmaf(zv.x, zv.x, zsq[0]);
    zsq[1] = fmaf(zv.y, zv.y, zsq[1]);
    zsq[2] = fmaf(zv.z, zv.z, zsq[2]);
    zsq[3] = fmaf(zv.w, zv.w, zsq[3]);
  }

  float best[4] = {3.4e38f, 3.4e38f, 3.4e38f, 3.4e38f};
  int bidx[4] = {0, 0, 0, 0};

  for (int ch = 0; ch < 16; ++ch) {
    const int cbase = ch * 64;
    __syncthreads();   // previous chunk's Et reads done
    // stage E chunk from ET -> Et[d][code] (coalesced, no transpose needed)
#pragma unroll
    for (int p = 0; p < 8; ++p) {
      int idx = p * 256 + tid;
      int d = idx >> 4;
      int cc = idx & 15;
      float4 v = *(const float4*)(ET + (size_t)d * KC + cbase + cc * 4);
      *(float4*)(&Et[d][cc * 4]) = v;
    }
    __syncthreads();

    float acc[4][4];
#pragma unroll
    for (int i = 0; i < 4; ++i)
#pragma unroll
      for (int j = 0; j < 4; ++j) acc[i][j] = 0.f;

#pragma unroll 8
    for (int k = 0; k < 128; ++k) {
      float4 zv = *(const float4*)(&Zt[k][tx * 4]);
      float4 ev = *(const float4*)(&Et[k][ty * 4]);
      acc[0][0] = fmaf(zv.x, ev.x, acc[0][0]);
      acc[0][1] = fmaf(zv.x, ev.y, acc[0][1]);
      acc[0][2] = fmaf(zv.x, ev.z, acc[0][2]);
      acc[0][3] = fmaf(zv.x, ev.w, acc[0][3]);
      acc[1][0] = fmaf(zv.y, ev.x, acc[1][0]);
      acc[1][1] = fmaf(zv.y, ev.y, acc[1][1]);
      acc[1][2] = fmaf(zv.y, ev.z, acc[1][2]);
      acc[1][3] = fmaf(zv.y, ev.w, acc[1][3]);
      acc[2][0] = fmaf(zv.z, ev.x, acc[2][0]);
      acc[2][1] = fmaf(zv.z, ev.y, acc[2][1]);
      acc[2][2] = fmaf(zv.z, ev.z, acc[2][2]);
      acc[2][3] = fmaf(zv.z, ev.w, acc[2][3]);
      acc[3][0] = fmaf(zv.w, ev.x, acc[3][0]);
      acc[3][1] = fmaf(zv.w, ev.y, acc[3][1]);
      acc[3][2] = fmaf(zv.w, ev.z, acc[3][2]);
      acc[3][3] = fmaf(zv.w, ev.w, acc[3][3]);
    }

    // finalize keys; ascending c within thread + strict < => first-index tie-break
#pragma unroll
    for (int j = 0; j < 4; ++j) {
      int c = cbase + ty * 4 + j;
      float eq = esq[c];
#pragma unroll
      for (int i = 0; i < 4; ++i) {
        float key = (zsq[i] + eq) - 2.0f * acc[i][j];   // reference expr tree
        if (key < best[i]) { best[i] = key; bidx[i] = c; }
      }
    }
  }

  // per-thread candidates -> LDS
#pragma unroll
  for (int i = 0; i < 4; ++i) {
    cval[ty][tx * 4 + i] = best[i];
    cidx[ty][tx * 4 + i] = bidx[i];
  }
  __syncthreads();

  // combine 16 candidates per row, lexicographic (val, idx)
  if (tid < 64) {
    float fb = cval[0][tid];
    int fi = cidx[0][tid];
#pragma unroll
    for (int j = 1; j < 16; ++j) {
      float v = cval[j][tid];
      int ii = cidx[j][tid];
      if (v < fb || (v == fb && ii < fi)) { fb = v; fi = ii; }
    }
    idx_out[r0 + tid] = fi;
    atomicAdd(&counts[fi], 1.0f);   // integer-valued fp32: exact
    fidx[tid] = fi;
  }
  __syncthreads();

  // scatter weighted sums: 4 threads per row, 32 dims each
  {
    int r = tid & 63;
    int h = tid >> 6;
    int fi = fidx[r];
    float* wrow = wsum + (size_t)fi * DD;
#pragma unroll
    for (int dd = 0; dd < 32; ++dd) {
      int d = h * 32 + dd;
      atomicAdd(&wrow[d], Zt[d][r]);
    }
  }
}

// Kernel 2: cluster-size EMA, dead detection, threefry restart indices, smoothing
__global__ __launch_bounds__(1024) void k_cluster(const float* __restrict__ counts,
                                                  const float* __restrict__ cs_in,
                                                  float* __restrict__ smooth,
                                                  int* __restrict__ ridx,
                                                  int* __restrict__ deadf) {
  const int k = threadIdx.x;   // 1024 threads, 1 block
  float c = counts[k];
  float t1 = 0.99f * cs_in[k];
  float t2 = 0.01f * c;        // f32(1.0 - 0.99) == f32(0.01)
  float nc = t1 + t2;
  bool dead = nc < 0.5f;

  uint32_t bits;
#if THREEFRY_PARTITIONABLE
  {
    uint32_t o0, o1;
    threefry2x32(0u, 42u, 0u, (uint32_t)k, &o0, &o1);  // counter = (hi=0, lo=k)
    bits = o0 ^ o1;
  }
#else
  {
    uint32_t o0, o1;
    if (k < 512) { threefry2x32(0u, 42u, (uint32_t)k, (uint32_t)(k + 512), &o0, &o1); bits = o0; }
    else         { threefry2x32(0u, 42u, (uint32_t)(k - 512), (uint32_t)k, &o0, &o1); bits = o1; }
  }
#endif
  int r = (int)(bits & 0x7FFFu);   // span=32768 (pow2): randint == bits mod 2^15

  float rep = dead ? 0.5f : nc;

  __shared__ float red[1024];
  red[k] = rep;
  __syncthreads();
  for (int s = 512; s > 0; s >>= 1) {
    if (k < s) red[k] += red[k + s];
    __syncthreads();
  }
  float n = red[0];

  float sm = ((rep + 1e-5f) / (n + 0.01024f)) * n;   // (nc+EPS)/(n+K*EPS)*n
  smooth[k] = sm;
  ridx[k] = r;
  deadf[k] = dead ? 1 : 0;
}

// Kernel 3: new embedding = (EMA avg or restart vec) / smoothed
__global__ __launch_bounds__(256) void k_emb(const float* __restrict__ wsum,
                                             const float* __restrict__ avg_in,
                                             const float* __restrict__ Z,
                                             const float* __restrict__ smooth,
                                             const int* __restrict__ ridx,
                                             const int* __restrict__ deadf,
                                             float* __restrict__ nemb) {
  int kd = blockIdx.x * 256 + threadIdx.x;   // < 131072
  int k = kd >> 7;
  int d = kd & (DD - 1);
  float t1 = 0.99f * avg_in[kd];
  float t2 = 0.01f * wsum[kd];
  float na = t1 + t2;
  if (deadf[k]) {
    int r = ridx[k];
    float zv = Z[((size_t)(r >> 12) * DD + d) * LL + (r & (LL - 1))];
    na = zv * 0.5f;   // rvec * RESTART_THRESHOLD
  }
  nemb[kd] = na / smooth[k];
}

// Kernel 4: gather z_q, write z_q_st + indices_map, accumulate squared-error
__global__ __launch_bounds__(256) void k_out(const float* __restrict__ Z,
                                             const float* __restrict__ nemb,
                                             const int* __restrict__ idxs,
                                             float* __restrict__ out,
                                             double* __restrict__ lacc) {
  int t = blockIdx.x * 256 + threadIdx.x;   // 1048576 threads, 4 l-elems each
  int l4 = t & (LL / 4 - 1);                // 1024
  int d = (t >> 10) & (DD - 1);
  int b = t >> 17;
  size_t zoff = ((size_t)(b * DD + d)) * LL + (size_t)l4 * 4;
  const float4 ze = *(const float4*)(Z + zoff);
  int n0 = b * LL + l4 * 4;
  int i0 = idxs[n0 + 0], i1 = idxs[n0 + 1], i2 = idxs[n0 + 2], i3 = idxs[n0 + 3];
  float q0 = nemb[(size_t)i0 * DD + d];
  float q1 = nemb[(size_t)i1 * DD + d];
  float q2 = nemb[(size_t)i2 * DD + d];
  float q3 = nemb[(size_t)i3 * DD + d];
  float4 o;
  o.x = ze.x + (q0 - ze.x);   // z_q_st = z_e + (z_q - z_e), reference expr tree
  o.y = ze.y + (q1 - ze.y);
  o.z = ze.z + (q2 - ze.z);
  o.w = ze.w + (q3 - ze.w);
  *(float4*)(out + zoff) = o;
  if (d == 0) {
    float* oi = out + (size_t)ZTOT;
    oi[n0 + 0] = (float)i0;
    oi[n0 + 1] = (float)i1;
    oi[n0 + 2] = (float)i2;
    oi[n0 + 3] = (float)i3;
  }
  float d0 = ze.x - q0, d1 = ze.y - q1, d2 = ze.z - q2, d3 = ze.w - q3;
  float s = d0 * d0 + d1 * d1 + d2 * d2 + d3 * d3;
  for (int off = 32; off > 0; off >>= 1) s += __shfl_down(s, off, 64);
  __shared__ float wsums[4];
  if ((threadIdx.x & 63) == 0) wsums[threadIdx.x >> 6] = s;
  __syncthreads();
  if (threadIdx.x == 0) {
    float tot = (wsums[0] + wsums[1]) + (wsums[2] + wsums[3]);
    atomicAdd(lacc, (double)tot);
  }
}

// Kernel 5: final loss scalars
__global__ void k_fin(const double* __restrict__ lacc, float* __restrict__ out) {
  double S = lacc[0];
  float cb = (float)(S / (double)ZTOT);   // codebook_loss == commitment_loss numerically
  float bc = 0.25f * cb;
  float vq = cb + bc;
  float* o = out + (size_t)ZTOT + NN;
  o[0] = vq;
  o[1] = cb;
  o[2] = bc;
}

extern "C" void kernel_launch(void* const* d_in, const int* in_sizes, int n_in,
                              void* d_out, int out_size, void* d_ws, size_t ws_size,
                              hipStream_t stream) {
  const float* Z  = (const float*)d_in[0];   // z_e        (8,128,4096)
  const float* E  = (const float*)d_in[1];   // embedding  (1024,128)
  const float* CS = (const float*)d_in[2];   // cluster_size (1024,)
  const float* EA = (const float*)d_in[3];   // embedding_avg (1024,128)
  float* out = (float*)d_out;
  float* ws = (float*)d_ws;

  float* counts = ws;                        // 1024
  float* esq    = ws + 1024;                 // 1024
  float* smooth = ws + 2048;                 // 1024
  int*   ridx   = (int*)(ws + 3072);         // 1024
  int*   deadf  = (int*)(ws + 4096);         // 1024
  float* wsum   = ws + 8192;                 // 131072
  float* nemb   = ws + 8192 + 131072;        // 131072 floats (512 KB)
  int*   idxs   = (int*)(ws + 270336);       // 32768
  double* lacc  = (double*)(ws + 303104);    // byte offset 1212416, 8B aligned

  // ET (transposed codebook, 512 KB) reuses the nemb slot: it is consumed by
  // k_dist and only afterwards does k_emb overwrite nemb (stream-ordered).
  float* ET = nemb;

  k_prep<<<KC, DD, 0, stream>>>(E, esq, wsum, counts, lacc, ET);
  k_dist<<<NN / 64, 256, 0, stream>>>(Z, ET, esq, idxs, counts, wsum);
  k_cluster<<<1, KC, 0, stream>>>(counts, CS, smooth, ridx, deadf);
  k_emb<<<(KC * DD) / 256, 256, 0, stream>>>(wsum, EA, Z, smooth, ridx, deadf, nemb);
  k_out<<<(ZTOT / 4) / 256, 256, 0, stream>>>(Z, nemb, idxs, out, lacc);
  k_fin<<<1, 1, 0, stream>>>(lacc, out);
}